// Round 8
// baseline (109.413 us; speedup 1.0000x reference)
//
#include <hip/hip_runtime.h>

typedef __bf16 bf16_t;
typedef bf16_t bf16x8 __attribute__((ext_vector_type(8)));
typedef float  f32x4  __attribute__((ext_vector_type(4)));

#define GAS __attribute__((address_space(1)))
#define LAS __attribute__((address_space(3)))

static constexpr int Nn = 8, Cc = 512, Hi = 32, Wi = 32, Oo = 512;
static constexpr int HO = 28, WO = 28;
static constexpr int NPOS = HO * WO;          // 784
static constexpr int MY = Nn * NPOS;          // 6272 = 49*128
static constexpr int M_ROWS = Nn * Hi * Wi;   // 8192

__device__ __forceinline__ float bf2f(unsigned short u) {
  union { unsigned int i; float f; } v; v.i = ((unsigned int)u) << 16; return v.f;
}
__device__ __forceinline__ unsigned short f2bf(float f) {
  union { float f; unsigned int u; } v; v.f = f;
  unsigned int u = v.u;
  return (unsigned short)((u + 0x7fffu + ((u >> 16) & 1u)) >> 16);  // RNE
}
__device__ __forceinline__ uint4 pack8(float4 f0, float4 f1) {
  uint4 r;
  r.x = (unsigned)f2bf(f0.x) | ((unsigned)f2bf(f0.y) << 16);
  r.y = (unsigned)f2bf(f0.z) | ((unsigned)f2bf(f0.w) << 16);
  r.z = (unsigned)f2bf(f1.x) | ((unsigned)f2bf(f1.y) << 16);
  r.w = (unsigned)f2bf(f1.z) | ((unsigned)f2bf(f1.w) << 16);
  return r;
}

// ---------------- prep: score GEMV (fp32 exact) + W fp32->bf16 ----------------
__global__ __launch_bounds__(256) void prep_kern(
    const float* __restrict__ X, const float* __restrict__ Wf,
    const float* __restrict__ Sw, const float* __restrict__ Sb,
    unsigned short* __restrict__ Wb, float* __restrict__ S)
{
  const int lane = threadIdx.x & 63;
  const int wave = threadIdx.x >> 6;
  const int bid  = blockIdx.x;
  if (bid < M_ROWS / 4) {
    const int m = bid * 4 + wave;
    const float* xf = X + (size_t)m * Cc + lane * 8;
    const float4 x0 = *(const float4*)xf, x1 = *(const float4*)(xf + 4);
    const float* wf = Sw + lane * 8;
    const float4 w0 = *(const float4*)wf, w1 = *(const float4*)(wf + 4);
    float s = x0.x * w0.x + x0.y * w0.y + x0.z * w0.z + x0.w * w0.w
            + x1.x * w1.x + x1.y * w1.y + x1.z * w1.z + x1.w * w1.w;
    #pragma unroll
    for (int off = 32; off > 0; off >>= 1) s += __shfl_down(s, off, 64);
    if (lane == 0) S[m] = s + Sb[0];
  } else {
    const int r = (bid - M_ROWS / 4) * 4 + wave;
    const float* wf = Wf + (size_t)r * Cc + lane * 8;
    const float4 f0 = *(const float4*)wf, f1 = *(const float4*)(wf + 4);
    *(uint4*)(Wb + (size_t)r * Cc + lane * 8) = pack8(f0, f1);
  }
}

// ---------------- attnY: LN+softmax weights, Y = sum_k a_k * X[pos_k]  ----------------
// block = (g = 16-ch group, n). Yt layout: [g][n*784+pos][16] bf16 (group-blocked
// so each block's writes are one contiguous 25 KB region; gemm re-gathers).
__global__ __launch_bounds__(256) void attnY_kern(
    const float* __restrict__ X, const float* __restrict__ S,
    const float* __restrict__ lnw, const float* __restrict__ lnb,
    unsigned short* __restrict__ Yt)
{
  const int g = blockIdx.x;   // 0..31
  const int n = blockIdx.y;   // 0..7
  const int t = threadIdx.x;

  __shared__ unsigned short Xt[Hi * Wi * 16];  // 32 KiB: [row][16 ch] bf16
  __shared__ float sl[Hi * Wi];                // 4 KiB
  __shared__ float lwv[25], lbv[25];

  // stage X ch-slice -> bf16 LDS: 2048 8-ch chunks
  #pragma unroll
  for (int itr = 0; itr < 8; itr++) {
    const int id = itr * 256 + t;
    const int row = id >> 1, ch8 = (id & 1) * 8;
    const float* xp = X + ((size_t)n * Hi * Wi + row) * Cc + g * 16 + ch8;
    const float4 f0 = *(const float4*)xp, f1 = *(const float4*)(xp + 4);
    *(uint4*)&Xt[row * 16 + ch8] = pack8(f0, f1);
  }
  #pragma unroll
  for (int k = 0; k < 4; k++) sl[k * 256 + t] = S[n * Hi * Wi + k * 256 + t];
  if (t < 25) { lwv[t] = lnw[t]; lbv[t] = lnb[t]; }
  __syncthreads();

  for (int itp = 0; itp < 4; itp++) {
    const int pos = itp * 256 + t;
    if (pos < NPOS) {
      const int i = pos / WO;
      const int j = pos - i * WO;

      float v[25], mu = 0.f;
      #pragma unroll
      for (int q = 0; q < 25; q++) { v[q] = sl[(i + q / 5) * Wi + j + q % 5]; mu += v[q]; }
      mu *= (1.0f / 25.0f);
      float var = 0.f;
      #pragma unroll
      for (int q = 0; q < 25; q++) { const float d = v[q] - mu; var += d * d; }
      var *= (1.0f / 25.0f);
      const float rr = rsqrtf(var + 1e-5f);
      float mx = -1e30f;
      #pragma unroll
      for (int q = 0; q < 25; q++) { v[q] = (v[q] - mu) * rr * lwv[q] + lbv[q]; mx = fmaxf(mx, v[q]); }
      float den = 0.f;
      #pragma unroll
      for (int q = 0; q < 25; q++) { v[q] = __expf(v[q] - mx); den += v[q]; }
      const float inv = 1.0f / den;

      float acc[16];
      #pragma unroll
      for (int c = 0; c < 16; c++) acc[c] = 0.f;
      #pragma unroll
      for (int ki = 0; ki < 5; ki++) {
        const int rb = (i + ki) * Wi + j;
        #pragma unroll
        for (int kj = 0; kj < 5; kj++) {
          const uint4* pr = (const uint4*)&Xt[(rb + kj) * 16];
          const uint4 a = pr[0], b = pr[1];
          const float wv = v[ki * 5 + kj] * inv;
          acc[0]  += bf2f((unsigned short)(a.x & 0xFFFFu)) * wv;
          acc[1]  += bf2f((unsigned short)(a.x >> 16)) * wv;
          acc[2]  += bf2f((unsigned short)(a.y & 0xFFFFu)) * wv;
          acc[3]  += bf2f((unsigned short)(a.y >> 16)) * wv;
          acc[4]  += bf2f((unsigned short)(a.z & 0xFFFFu)) * wv;
          acc[5]  += bf2f((unsigned short)(a.z >> 16)) * wv;
          acc[6]  += bf2f((unsigned short)(a.w & 0xFFFFu)) * wv;
          acc[7]  += bf2f((unsigned short)(a.w >> 16)) * wv;
          acc[8]  += bf2f((unsigned short)(b.x & 0xFFFFu)) * wv;
          acc[9]  += bf2f((unsigned short)(b.x >> 16)) * wv;
          acc[10] += bf2f((unsigned short)(b.y & 0xFFFFu)) * wv;
          acc[11] += bf2f((unsigned short)(b.y >> 16)) * wv;
          acc[12] += bf2f((unsigned short)(b.z & 0xFFFFu)) * wv;
          acc[13] += bf2f((unsigned short)(b.z >> 16)) * wv;
          acc[14] += bf2f((unsigned short)(b.w & 0xFFFFu)) * wv;
          acc[15] += bf2f((unsigned short)(b.w >> 16)) * wv;
        }
      }
      unsigned short* yp = Yt + ((size_t)g * MY + n * NPOS + pos) * 16;
      uint4 o0, o1;
      o0.x = (unsigned)f2bf(acc[0])  | ((unsigned)f2bf(acc[1])  << 16);
      o0.y = (unsigned)f2bf(acc[2])  | ((unsigned)f2bf(acc[3])  << 16);
      o0.z = (unsigned)f2bf(acc[4])  | ((unsigned)f2bf(acc[5])  << 16);
      o0.w = (unsigned)f2bf(acc[6])  | ((unsigned)f2bf(acc[7])  << 16);
      o1.x = (unsigned)f2bf(acc[8])  | ((unsigned)f2bf(acc[9])  << 16);
      o1.y = (unsigned)f2bf(acc[10]) | ((unsigned)f2bf(acc[11]) << 16);
      o1.z = (unsigned)f2bf(acc[12]) | ((unsigned)f2bf(acc[13]) << 16);
      o1.w = (unsigned)f2bf(acc[14]) | ((unsigned)f2bf(acc[15]) << 16);
      *(uint4*)yp = o0;
      *(uint4*)(yp + 8) = o1;
    }
  }
}

// ---------------- GEMM: out[n,o,pos] = sum_c Y[m,c]*Wb[o,c] + bias[o] ----------------
#define BM 128
#define BN 64
#define BK 32

__global__ __launch_bounds__(256) void gemm_out(
    const unsigned short* __restrict__ Yt, const bf16_t* __restrict__ Wb,
    const float* __restrict__ Bp, float* __restrict__ out)
{
  __shared__ bf16_t lA[BM * BK];   // 8 KiB
  __shared__ bf16_t lB[BN * BK];   // 4 KiB
  const int t    = threadIdx.x;
  const int bm   = blockIdx.x;   // 0..48
  const int bn   = blockIdx.y;   // 0..7
  const int lane = t & 63;
  const int wave = t >> 6;
  const int wm   = (wave >> 1) * 64;
  const int wn   = (wave & 1) * 32;

  f32x4 acc[4][2];
  #pragma unroll
  for (int a = 0; a < 4; a++)
    #pragma unroll
    for (int b = 0; b < 2; b++) acc[a][b] = (f32x4){0.f, 0.f, 0.f, 0.f};

  // A-staging from group-blocked Yt: elem addr(rr,kk) = ((kk>>4)*MY + rr)*16 + (kk&15)
  const int r0 = t >> 2;          // LDS row
  const int c0 = (t & 3) * 8;     // k-chunk (never crosses a 16-boundary)
  const int rrA = bm * BM + r0;
  const bf16_t* Bg = Wb + (size_t)(bn * BN + r0) * Cc + c0;

  for (int k0 = 0; k0 < Cc; k0 += BK) {
    const int kk = k0 + c0;
    const unsigned short* Ag0 = Yt + ((size_t)(kk >> 4) * MY + rrA) * 16 + (kk & 15);
    __syncthreads();
    __builtin_amdgcn_global_load_lds((const GAS void*)Ag0,              (LAS void*)&lA[t * 8],         16, 0, 0);
    __builtin_amdgcn_global_load_lds((const GAS void*)(Ag0 + 64 * 16),  (LAS void*)&lA[(t + 256) * 8], 16, 0, 0);
    __builtin_amdgcn_global_load_lds((const GAS void*)(Bg + k0),        (LAS void*)&lB[t * 8],         16, 0, 0);
    __syncthreads();

    const int kof = (lane >> 4) * 8;
    bf16x8 af[4], bfr[2];
    #pragma unroll
    for (int mt = 0; mt < 4; mt++)
      af[mt] = *(const bf16x8*)&lA[(wm + mt * 16 + (lane & 15)) * BK + kof];
    #pragma unroll
    for (int nt = 0; nt < 2; nt++)
      bfr[nt] = *(const bf16x8*)&lB[(wn + nt * 16 + (lane & 15)) * BK + kof];
    #pragma unroll
    for (int mt = 0; mt < 4; mt++)
      #pragma unroll
      for (int nt = 0; nt < 2; nt++)
        acc[mt][nt] = __builtin_amdgcn_mfma_f32_16x16x32_bf16(af[mt], bfr[nt], acc[mt][nt], 0, 0, 0);
  }

  // epilogue: C/D layout col=lane&15 (o), row=(lane>>4)*4+r (m = n*784+pos).
  // 784 % 4 == 0 -> a 4-row register group never straddles n; float4 store.
  #pragma unroll
  for (int nt = 0; nt < 2; nt++) {
    const int col = bn * BN + wn + nt * 16 + (lane & 15);
    const float bias = Bp[col];
    #pragma unroll
    for (int mt = 0; mt < 4; mt++) {
      const int rr0 = bm * BM + wm + mt * 16 + (lane >> 4) * 4;
      const int n0  = rr0 / NPOS;
      const int pos0 = rr0 - n0 * NPOS;
      float4 q;
      q.x = acc[mt][nt][0] + bias;
      q.y = acc[mt][nt][1] + bias;
      q.z = acc[mt][nt][2] + bias;
      q.w = acc[mt][nt][3] + bias;
      *(float4*)&out[((size_t)n0 * Oo + col) * NPOS + pos0] = q;
    }
  }
}

extern "C" void kernel_launch(void* const* d_in, const int* in_sizes, int n_in,
                              void* d_out, int out_size, void* d_ws, size_t ws_size,
                              hipStream_t stream) {
  const float* x   = (const float*)d_in[0];
  const float* pw  = (const float*)d_in[1];
  const float* pb  = (const float*)d_in[2];
  const float* sw  = (const float*)d_in[3];
  const float* sb  = (const float*)d_in[4];
  const float* lnw = (const float*)d_in[5];
  const float* lnb = (const float*)d_in[6];

  char* w = (char*)d_ws;
  float*          Sv = (float*)w;                              // 32 KiB
  unsigned short* Wb = (unsigned short*)(w + (64 << 10));      // 512 KiB
  unsigned short* Yt = (unsigned short*)(w + (1 << 20));       // 6.4 MiB: [32][6272][16] bf16

  prep_kern<<<dim3(M_ROWS / 4 + Oo / 4), 256, 0, stream>>>(x, pw, sw, sb, Wb, Sv);
  attnY_kern<<<dim3(Oo / 16, Nn), 256, 0, stream>>>(x, Sv, lnw, lnb, Yt);
  gemm_out<<<dim3(MY / BM, Oo / BN), 256, 0, stream>>>(Yt, (const bf16_t*)Wb, pb, (float*)d_out);
}

// Round 9
// 108.519 us; speedup vs baseline: 1.0082x; 1.0082x over previous
//
#include <hip/hip_runtime.h>

typedef __bf16 bf16_t;
typedef bf16_t bf16x8 __attribute__((ext_vector_type(8)));
typedef float  f32x4  __attribute__((ext_vector_type(4)));

#define GAS __attribute__((address_space(1)))
#define LAS __attribute__((address_space(3)))

static constexpr int Nn = 8, Cc = 512, Hi = 32, Wi = 32, Oo = 512;
static constexpr int HO = 28, WO = 28;
static constexpr int NPOS = HO * WO;          // 784
static constexpr int MY = Nn * NPOS;          // 6272 = 98*64
static constexpr int M_ROWS = Nn * Hi * Wi;   // 8192

__device__ __forceinline__ float bf2f(unsigned short u) {
  union { unsigned int i; float f; } v; v.i = ((unsigned int)u) << 16; return v.f;
}
__device__ __forceinline__ unsigned short f2bf(float f) {
  union { float f; unsigned int u; } v; v.f = f;
  unsigned int u = v.u;
  return (unsigned short)((u + 0x7fffu + ((u >> 16) & 1u)) >> 16);  // RNE
}
__device__ __forceinline__ uint4 pack8(float4 f0, float4 f1) {
  uint4 r;
  r.x = (unsigned)f2bf(f0.x) | ((unsigned)f2bf(f0.y) << 16);
  r.y = (unsigned)f2bf(f0.z) | ((unsigned)f2bf(f0.w) << 16);
  r.z = (unsigned)f2bf(f1.x) | ((unsigned)f2bf(f1.y) << 16);
  r.w = (unsigned)f2bf(f1.z) | ((unsigned)f2bf(f1.w) << 16);
  return r;
}

// ---------------- prep: score GEMV (fp32 exact) + W fp32->bf16 ----------------
__global__ __launch_bounds__(256) void prep_kern(
    const float* __restrict__ X, const float* __restrict__ Wf,
    const float* __restrict__ Sw, const float* __restrict__ Sb,
    unsigned short* __restrict__ Wb, float* __restrict__ S)
{
  const int lane = threadIdx.x & 63;
  const int wave = threadIdx.x >> 6;
  const int bid  = blockIdx.x;
  if (bid < M_ROWS / 4) {
    const int m = bid * 4 + wave;
    const float* xf = X + (size_t)m * Cc + lane * 8;
    const float4 x0 = *(const float4*)xf, x1 = *(const float4*)(xf + 4);
    const float* wf = Sw + lane * 8;
    const float4 w0 = *(const float4*)wf, w1 = *(const float4*)(wf + 4);
    float s = x0.x * w0.x + x0.y * w0.y + x0.z * w0.z + x0.w * w0.w
            + x1.x * w1.x + x1.y * w1.y + x1.z * w1.z + x1.w * w1.w;
    #pragma unroll
    for (int off = 32; off > 0; off >>= 1) s += __shfl_down(s, off, 64);
    if (lane == 0) S[m] = s + Sb[0];
  } else {
    const int r = (bid - M_ROWS / 4) * 4 + wave;
    const float* wf = Wf + (size_t)r * Cc + lane * 8;
    const float4 f0 = *(const float4*)wf, f1 = *(const float4*)(wf + 4);
    *(uint4*)(Wb + (size_t)r * Cc + lane * 8) = pack8(f0, f1);
  }
}

// ---------------- attnY: LN+softmax weights, Y = sum_k a_k * X[pos_k]  ----------------
// block = (g = 16-ch group, n). Yt layout: [g][n*784+pos][16] bf16.
__global__ __launch_bounds__(256) void attnY_kern(
    const float* __restrict__ X, const float* __restrict__ S,
    const float* __restrict__ lnw, const float* __restrict__ lnb,
    unsigned short* __restrict__ Yt)
{
  const int g = blockIdx.x;   // 0..31
  const int n = blockIdx.y;   // 0..7
  const int t = threadIdx.x;

  __shared__ unsigned short Xt[Hi * Wi * 16];  // 32 KiB
  __shared__ float sl[Hi * Wi];                // 4 KiB
  __shared__ float lwv[25], lbv[25];

  #pragma unroll
  for (int itr = 0; itr < 8; itr++) {
    const int id = itr * 256 + t;
    const int row = id >> 1, ch8 = (id & 1) * 8;
    const float* xp = X + ((size_t)n * Hi * Wi + row) * Cc + g * 16 + ch8;
    const float4 f0 = *(const float4*)xp, f1 = *(const float4*)(xp + 4);
    *(uint4*)&Xt[row * 16 + ch8] = pack8(f0, f1);
  }
  #pragma unroll
  for (int k = 0; k < 4; k++) sl[k * 256 + t] = S[n * Hi * Wi + k * 256 + t];
  if (t < 25) { lwv[t] = lnw[t]; lbv[t] = lnb[t]; }
  __syncthreads();

  for (int itp = 0; itp < 4; itp++) {
    const int pos = itp * 256 + t;
    if (pos < NPOS) {
      const int i = pos / WO;
      const int j = pos - i * WO;

      float v[25], mu = 0.f;
      #pragma unroll
      for (int q = 0; q < 25; q++) { v[q] = sl[(i + q / 5) * Wi + j + q % 5]; mu += v[q]; }
      mu *= (1.0f / 25.0f);
      float var = 0.f;
      #pragma unroll
      for (int q = 0; q < 25; q++) { const float d = v[q] - mu; var += d * d; }
      var *= (1.0f / 25.0f);
      const float rr = rsqrtf(var + 1e-5f);
      float mx = -1e30f;
      #pragma unroll
      for (int q = 0; q < 25; q++) { v[q] = (v[q] - mu) * rr * lwv[q] + lbv[q]; mx = fmaxf(mx, v[q]); }
      float den = 0.f;
      #pragma unroll
      for (int q = 0; q < 25; q++) { v[q] = __expf(v[q] - mx); den += v[q]; }
      const float inv = 1.0f / den;

      float acc[16];
      #pragma unroll
      for (int c = 0; c < 16; c++) acc[c] = 0.f;
      #pragma unroll
      for (int ki = 0; ki < 5; ki++) {
        const int rb = (i + ki) * Wi + j;
        #pragma unroll
        for (int kj = 0; kj < 5; kj++) {
          const uint4* pr = (const uint4*)&Xt[(rb + kj) * 16];
          const uint4 a = pr[0], b = pr[1];
          const float wv = v[ki * 5 + kj] * inv;
          acc[0]  += bf2f((unsigned short)(a.x & 0xFFFFu)) * wv;
          acc[1]  += bf2f((unsigned short)(a.x >> 16)) * wv;
          acc[2]  += bf2f((unsigned short)(a.y & 0xFFFFu)) * wv;
          acc[3]  += bf2f((unsigned short)(a.y >> 16)) * wv;
          acc[4]  += bf2f((unsigned short)(a.z & 0xFFFFu)) * wv;
          acc[5]  += bf2f((unsigned short)(a.z >> 16)) * wv;
          acc[6]  += bf2f((unsigned short)(a.w & 0xFFFFu)) * wv;
          acc[7]  += bf2f((unsigned short)(a.w >> 16)) * wv;
          acc[8]  += bf2f((unsigned short)(b.x & 0xFFFFu)) * wv;
          acc[9]  += bf2f((unsigned short)(b.x >> 16)) * wv;
          acc[10] += bf2f((unsigned short)(b.y & 0xFFFFu)) * wv;
          acc[11] += bf2f((unsigned short)(b.y >> 16)) * wv;
          acc[12] += bf2f((unsigned short)(b.z & 0xFFFFu)) * wv;
          acc[13] += bf2f((unsigned short)(b.z >> 16)) * wv;
          acc[14] += bf2f((unsigned short)(b.w & 0xFFFFu)) * wv;
          acc[15] += bf2f((unsigned short)(b.w >> 16)) * wv;
        }
      }
      unsigned short* yp = Yt + ((size_t)g * MY + n * NPOS + pos) * 16;
      uint4 o0, o1;
      o0.x = (unsigned)f2bf(acc[0])  | ((unsigned)f2bf(acc[1])  << 16);
      o0.y = (unsigned)f2bf(acc[2])  | ((unsigned)f2bf(acc[3])  << 16);
      o0.z = (unsigned)f2bf(acc[4])  | ((unsigned)f2bf(acc[5])  << 16);
      o0.w = (unsigned)f2bf(acc[6])  | ((unsigned)f2bf(acc[7])  << 16);
      o1.x = (unsigned)f2bf(acc[8])  | ((unsigned)f2bf(acc[9])  << 16);
      o1.y = (unsigned)f2bf(acc[10]) | ((unsigned)f2bf(acc[11]) << 16);
      o1.z = (unsigned)f2bf(acc[12]) | ((unsigned)f2bf(acc[13]) << 16);
      o1.w = (unsigned)f2bf(acc[14]) | ((unsigned)f2bf(acc[15]) << 16);
      *(uint4*)yp = o0;
      *(uint4*)(yp + 8) = o1;
    }
  }
}

// ---------------- GEMM: out[n,o,pos] = sum_c Y[m,c]*Wb[o,c] + bias[o] ----------------
// 64x64 tiles -> 784 blocks (~3/CU). LDS-transpose epilogue for pos-contiguous stores.
#define BM 64
#define BN 64
#define BK 32

__global__ __launch_bounds__(256) void gemm_out(
    const unsigned short* __restrict__ Yt, const bf16_t* __restrict__ Wb,
    const float* __restrict__ Bp, float* __restrict__ out)
{
  __shared__ bf16_t lA[BM * BK];       // 4 KiB
  __shared__ bf16_t lB[BN * BK];       // 4 KiB
  __shared__ float  ldsC[BM * 65];     // 16.25 KiB, pad 65 -> conflict-free col reads
  const int t    = threadIdx.x;
  const int bm   = blockIdx.x;   // 0..97
  const int bn   = blockIdx.y;   // 0..7
  const int lane = t & 63;
  const int wave = t >> 6;
  const int wm   = (wave >> 1) * 32;
  const int wn   = (wave & 1) * 32;

  f32x4 acc[2][2];
  #pragma unroll
  for (int a = 0; a < 2; a++)
    #pragma unroll
    for (int b = 0; b < 2; b++) acc[a][b] = (f32x4){0.f, 0.f, 0.f, 0.f};

  // staging: thread t covers LDS row r0=t>>2, k-chunk (t&3)*8 (one load each)
  const int r0 = t >> 2;
  const int c0 = (t & 3) * 8;
  const int rrA = bm * BM + r0;
  const bf16_t* Bg = Wb + (size_t)(bn * BN + r0) * Cc + c0;

  for (int k0 = 0; k0 < Cc; k0 += BK) {
    const int kk = k0 + c0;   // (kk&15) in {0,8}: 8-chunks never cross the 16-ch group
    const unsigned short* Ag0 = Yt + ((size_t)(kk >> 4) * MY + rrA) * 16 + (kk & 15);
    __syncthreads();
    __builtin_amdgcn_global_load_lds((const GAS void*)Ag0, (LAS void*)&lA[t * 8], 16, 0, 0);
    __builtin_amdgcn_global_load_lds((const GAS void*)Bg,  (LAS void*)&lB[t * 8], 16, 0, 0);
    Bg += BK;
    __syncthreads();

    const int kof = (lane >> 4) * 8;
    bf16x8 af[2], bfr[2];
    #pragma unroll
    for (int mt = 0; mt < 2; mt++)
      af[mt] = *(const bf16x8*)&lA[(wm + mt * 16 + (lane & 15)) * BK + kof];
    #pragma unroll
    for (int nt = 0; nt < 2; nt++)
      bfr[nt] = *(const bf16x8*)&lB[(wn + nt * 16 + (lane & 15)) * BK + kof];
    #pragma unroll
    for (int mt = 0; mt < 2; mt++)
      #pragma unroll
      for (int nt = 0; nt < 2; nt++)
        acc[mt][nt] = __builtin_amdgcn_mfma_f32_16x16x32_bf16(af[mt], bfr[nt], acc[mt][nt], 0, 0, 0);
  }

  // write accumulators to ldsC[row][col] (C/D: col=lane&15, row=(lane>>4)*4+r)
  #pragma unroll
  for (int mt = 0; mt < 2; mt++)
    #pragma unroll
    for (int nt = 0; nt < 2; nt++) {
      const int row = wm + mt * 16 + (lane >> 4) * 4;
      const int col = wn + nt * 16 + (lane & 15);
      #pragma unroll
      for (int r = 0; r < 4; r++)
        ldsC[(row + r) * 65 + col] = acc[mt][nt][r];
    }
  __syncthreads();

  // wave w stores cols w*16..w*16+15; lanes = 64 consecutive pos -> 256-B segments
  const int rr  = bm * BM + lane;
  const int n0  = rr / NPOS;
  const int pos0 = rr - n0 * NPOS;
  #pragma unroll
  for (int cc = 0; cc < 16; cc++) {
    const int col = bn * BN + wave * 16 + cc;
    const float val = ldsC[lane * 65 + wave * 16 + cc] + Bp[col];
    out[(size_t)(n0 * Oo + col) * NPOS + pos0] = val;
  }
}

extern "C" void kernel_launch(void* const* d_in, const int* in_sizes, int n_in,
                              void* d_out, int out_size, void* d_ws, size_t ws_size,
                              hipStream_t stream) {
  const float* x   = (const float*)d_in[0];
  const float* pw  = (const float*)d_in[1];
  const float* pb  = (const float*)d_in[2];
  const float* sw  = (const float*)d_in[3];
  const float* sb  = (const float*)d_in[4];
  const float* lnw = (const float*)d_in[5];
  const float* lnb = (const float*)d_in[6];

  char* w = (char*)d_ws;
  float*          Sv = (float*)w;                              // 32 KiB
  unsigned short* Wb = (unsigned short*)(w + (64 << 10));      // 512 KiB
  unsigned short* Yt = (unsigned short*)(w + (1 << 20));       // 6.4 MiB: [32][6272][16] bf16

  prep_kern<<<dim3(M_ROWS / 4 + Oo / 4), 256, 0, stream>>>(x, pw, sw, sb, Wb, Sv);
  attnY_kern<<<dim3(Oo / 16, Nn), 256, 0, stream>>>(x, Sv, lnw, lnb, Yt);
  gemm_out<<<dim3(MY / BM, Oo / BN), 256, 0, stream>>>(Yt, (const bf16_t*)Wb, pb, (float*)d_out);
}